// Round 1
// baseline (146.872 us; speedup 1.0000x reference)
//
#include <hip/hip_runtime.h>

// Problem constants
#define NB 8
#define NQ 2048
#define ND 256
#define NH 8
#define NL 3
#define NP 4
#define NHD 32
#define HLP 96
// level-major vproj row offsets: level l rows start at LOFF[l], row = LOFF[l] + b*T_l + t
// T = {2048,1024,512}; LOFF = {0, 16384, 24576}; total rows 28672

#define BM 64
#define BN 64
#define BKK 32
#define PADA 4

// C[M,N] = A[M,K] @ B[K,N] + bias[N]   (f32, tiled, 4x4 register tile)
__global__ __launch_bounds__(256) void gemm_bias_kernel(
    const float* __restrict__ A, int lda,
    const float* __restrict__ Bm, int ldb,
    const float* __restrict__ bias,
    float* __restrict__ C, int ldc,
    int M, int N, int K)
{
    __shared__ float As[BKK][BM + PADA];  // pad=4 keeps 16B alignment, kills store conflicts
    __shared__ float Bs[BKK][BN];

    const int t  = threadIdx.x;
    const int tx = t & 15;
    const int ty = t >> 4;
    const int row0 = blockIdx.y * BM;
    const int col0 = blockIdx.x * BN;

    const int a_rl = t >> 2;   // 0..63
    const int a_kg = t & 3;    // 0..3
    const int b_kr = t >> 4;   // 0..15
    const int b_cg = t & 15;   // 0..15

    float acc[4][4] = {};

    for (int k0 = 0; k0 < K; k0 += BKK) {
#pragma unroll
        for (int half = 0; half < 2; ++half) {
            const float4 av = *reinterpret_cast<const float4*>(
                &A[(size_t)(row0 + a_rl) * lda + k0 + half * 16 + a_kg * 4]);
            const int kb = half * 16 + a_kg * 4;
            As[kb + 0][a_rl] = av.x;
            As[kb + 1][a_rl] = av.y;
            As[kb + 2][a_rl] = av.z;
            As[kb + 3][a_rl] = av.w;
        }
#pragma unroll
        for (int half = 0; half < 2; ++half) {
            const float4 bv = *reinterpret_cast<const float4*>(
                &Bm[(size_t)(k0 + half * 16 + b_kr) * ldb + col0 + b_cg * 4]);
            *reinterpret_cast<float4*>(&Bs[half * 16 + b_kr][b_cg * 4]) = bv;
        }
        __syncthreads();
#pragma unroll
        for (int kk = 0; kk < BKK; ++kk) {
            const float4 a4 = *reinterpret_cast<const float4*>(&As[kk][ty * 4]);
            const float4 b4 = *reinterpret_cast<const float4*>(&Bs[kk][tx * 4]);
            const float ar[4] = {a4.x, a4.y, a4.z, a4.w};
            const float br[4] = {b4.x, b4.y, b4.z, b4.w};
#pragma unroll
            for (int i = 0; i < 4; ++i)
#pragma unroll
                for (int j = 0; j < 4; ++j)
                    acc[i][j] = fmaf(ar[i], br[j], acc[i][j]);
        }
        __syncthreads();
    }

#pragma unroll
    for (int i = 0; i < 4; ++i) {
        const int r = row0 + ty * 4 + i;
        float4 o;
        o.x = acc[i][0] + bias[col0 + tx * 4 + 0];
        o.y = acc[i][1] + bias[col0 + tx * 4 + 1];
        o.z = acc[i][2] + bias[col0 + tx * 4 + 2];
        o.w = acc[i][3] + bias[col0 + tx * 4 + 3];
        *reinterpret_cast<float4*>(&C[(size_t)r * ldc + col0 + tx * 4]) = o;
    }
}

// concatenate [Woff | Waw] -> Wcat [256][192], [boff|baw] -> bcat[192]
__global__ __launch_bounds__(256) void concat_w_kernel(
    const float* __restrict__ Woff, const float* __restrict__ Waw,
    const float* __restrict__ boff, const float* __restrict__ baw,
    float* __restrict__ Wcat, float* __restrict__ bcat)
{
    const int i = blockIdx.x * 256 + threadIdx.x;   // 0..49151
    const int k = i / 192, j = i % 192;
    Wcat[i] = (j < 96) ? Woff[k * 96 + j] : Waw[k * 96 + (j - 96)];
    if (i < 192) bcat[i] = (i < 96) ? boff[i] : baw[i - 96];
}

// per query: softmax the 96 aw logits per-head (12-wide), and turn the 96
// offsets into sample indices sidx = clip(ref + off/T, 0,1) * (T-1).
// rows layout per query: [0..95] aw logits -> aw, [96..191] off logits -> sidx
// NOTE: GEMM wrote [0..95]=off, [96..191]=aw; we swap roles on write.
__global__ __launch_bounds__(128) void softmax_sidx_kernel(
    const float* __restrict__ refpts, float* __restrict__ rows)
{
    const int bq = blockIdx.x;
    const int t = threadIdx.x;
    float* row = rows + (size_t)bq * 192;
    __shared__ float soff[96];
    __shared__ float sl[96];
    __shared__ float hm[8], hs[8];
    if (t < 96) { soff[t] = row[t]; sl[t] = row[96 + t]; }
    __syncthreads();
    if (t < 8) {
        float m = -1e30f;
        for (int j = 0; j < 12; ++j) m = fmaxf(m, sl[t * 12 + j]);
        hm[t] = m;
    }
    __syncthreads();
    if (t < 96) sl[t] = expf(sl[t] - hm[t / 12]);
    __syncthreads();
    if (t < 8) {
        float s = 0.f;
        for (int j = 0; j < 12; ++j) s += sl[t * 12 + j];
        hs[t] = s;
    }
    __syncthreads();
    if (t < 96) {
        row[t] = sl[t] / hs[t / 12];              // aw
        const int l = (t % 12) >> 2;
        const int T = 2048 >> l;
        const float ref = refpts[bq];
        float pos = ref + soff[t] / (float)T;
        pos = fminf(fmaxf(pos, 0.f), 1.f);
        row[96 + t] = pos * (float)(T - 1);        // sidx
    }
}

// gather + lerp + weighted sum:  out_mid[bq, h*32+c] = sum_{l,p} aw * lerp(vproj)
__global__ __launch_bounds__(256) void sample_kernel(
    const float* __restrict__ rows,   // [16384,192]  aw | sidx
    const float* __restrict__ vproj,  // [28672,128]  level-major
    float* __restrict__ out_mid)      // [16384,256]
{
    const int bq = blockIdx.x;
    const int b = bq >> 11;           // Q = 2048
    const int t = threadIdx.x;
    const int h = t >> 5, c = t & 31;
    __shared__ float srow[192];
    if (t < 192) srow[t] = rows[(size_t)bq * 192 + t];
    __syncthreads();
    float acc = 0.f;
#pragma unroll
    for (int l = 0; l < 3; ++l) {
        const int T = 2048 >> l;
        const int loff = (l == 0) ? 0 : ((l == 1) ? 16384 : 24576);
#pragma unroll
        for (int p = 0; p < 4; ++p) {
            const int j = h * 12 + l * 4 + p;
            const float w = srow[j];
            const float sidx = srow[96 + j];
            int ifl = (int)sidx;                 // sidx >= 0, trunc == floor
            ifl = min(max(ifl, 0), T - 2);
            const float wce = sidx - (float)ifl;
            const size_t base = ((size_t)(loff + b * T + ifl)) * 128 + p * 32 + c;
            const float vf = vproj[base];
            const float vc = vproj[base + 128];
            acc += w * (vf + wce * (vc - vf));
        }
    }
    out_mid[(size_t)bq * 256 + t] = acc;
}

extern "C" void kernel_launch(void* const* d_in, const int* in_sizes, int n_in,
                              void* d_out, int out_size, void* d_ws, size_t ws_size,
                              hipStream_t stream) {
    (void)in_sizes; (void)n_in; (void)out_size; (void)ws_size;
    const float* query = (const float*)d_in[0];
    const float* refp  = (const float*)d_in[1];
    const float* v0    = (const float*)d_in[2];
    const float* v1    = (const float*)d_in[3];
    const float* v2    = (const float*)d_in[4];
    const float* Woff  = (const float*)d_in[5];
    const float* boff  = (const float*)d_in[6];
    const float* Waw   = (const float*)d_in[7];
    const float* baw   = (const float*)d_in[8];
    const float* Wv    = (const float*)d_in[9];
    const float* bv    = (const float*)d_in[10];
    const float* Wo    = (const float*)d_in[11];
    const float* bo    = (const float*)d_in[12];
    float* out = (float*)d_out;

    char* ws = (char*)d_ws;
    float* vproj = (float*)(ws);                               // 28672*128 f32 = 14,680,064 B
    float* rows  = (float*)(ws + 14680064);                    // 16384*192 f32 = 12,582,912 B
    float* omid  = (float*)(ws + 14680064 + 12582912);         // 16384*256 f32 = 16,777,216 B
    // Wcat/bcat live inside the (not-yet-used) omid region: consumed in the
    // offset GEMM, which completes before sample_kernel writes omid.
    float* Wcat  = omid;                                       // 256*192 f32 = 196,608 B
    float* bcat  = (float*)((char*)omid + 196608);             // 192 f32

    // K0: weight concat
    concat_w_kernel<<<192, 256, 0, stream>>>(Woff, Waw, boff, baw, Wcat, bcat);

    // K1: value projections (only columns 0..127 of Wv are ever consumed:
    // the reference gathers v's head axis with the point index p < 4)
    gemm_bias_kernel<<<dim3(2, 256), 256, 0, stream>>>(v0, 256, Wv, 256, bv, vproj,              128, 16384, 128, 256);
    gemm_bias_kernel<<<dim3(2, 128), 256, 0, stream>>>(v1, 256, Wv, 256, bv, vproj + 16384*128,  128,  8192, 128, 256);
    gemm_bias_kernel<<<dim3(2,  64), 256, 0, stream>>>(v2, 256, Wv, 256, bv, vproj + 24576*128,  128,  4096, 128, 256);

    // K2a: offset + attention-weight logits
    gemm_bias_kernel<<<dim3(3, 256), 256, 0, stream>>>(query, 256, Wcat, 192, bcat, rows, 192, 16384, 192, 256);

    // K2b: per-head softmax + sample index computation
    softmax_sidx_kernel<<<16384, 128, 0, stream>>>(refp, rows);

    // K3: gather + lerp + weighted sum
    sample_kernel<<<16384, 256, 0, stream>>>(rows, vproj, omid);

    // K4: output projection
    gemm_bias_kernel<<<dim3(4, 256), 256, 0, stream>>>(omid, 256, Wo, 256, bo, out, 256, 16384, 256, 256);
}

// Round 2
// 82.358 us; speedup vs baseline: 1.7834x; 1.7834x over previous
//
#include <hip/hip_runtime.h>
#include <stdint.h>

// Problem constants
#define NB 8
#define NQ 2048
#define ND 256
// vproj rows: level-major, T={2048,1024,512}, LOFF={0,16384,24576}, total 28672

typedef __attribute__((ext_vector_type(8))) short bf16x8;
typedef __attribute__((ext_vector_type(8))) unsigned short u16x8;
typedef __attribute__((ext_vector_type(4))) float f32x4;

__device__ __forceinline__ unsigned short f2bf(float f) {
    union { float f; uint32_t u; } v; v.f = f;
    return (unsigned short)((v.u + 0x7FFFu + ((v.u >> 16) & 1u)) >> 16);  // RNE
}

// C[M,N] = A @ B + bias, f32 in/out, bf16 MFMA inside.
// A selected from {A0,A1,A2} by global row (fused multi-level value projection):
// rows [0,s0) -> A0, [s0,s1) -> A1, [s1,...) -> A2 (local row = global - start).
// Block tile 128x128, BK=32, 4 waves (2x2), wave tile 64x64.
// LDS layout: subtiled [slot][row][8k] so fragment reads are conflict-free b128.
__global__ __launch_bounds__(256) void gemm_mfma_kernel(
    const float* __restrict__ A0, const float* __restrict__ A1, const float* __restrict__ A2,
    int s0, int s1, int lda,
    const float* __restrict__ Bm, int ldb,
    const float* __restrict__ bias,
    float* __restrict__ C, int ldc, int Nstore, int K)
{
    __shared__ unsigned short Asub[4][128][8];  // 8 KB
    __shared__ unsigned short Bsub[4][128][8];  // 8 KB

    const int t = threadIdx.x;
    const int row0 = blockIdx.y * 128;   // global C row
    const int col0 = blockIdx.x * 128;   // global C col

    const float* Ap; int arow;
    if (row0 < s0)      { Ap = A0; arow = row0; }
    else if (row0 < s1) { Ap = A1; arow = row0 - s0; }
    else                { Ap = A2; arow = row0 - s1; }

    // A staging: thread -> (row ar, k-half ah); writes 2 b128 (one per slot pair)
    const int ar = t >> 1, ah = t & 1;
    // B staging: thread -> (col bc, slot-pair bq); strided f32 reads are
    // coalesced ACROSS lanes (consecutive cols), pack 8k -> one b128 write
    const int bc = t & 127, bq = t >> 7;

    const int w = t >> 6, lane = t & 63;
    const int wr = w >> 1, wc = w & 1;        // wave 2x2 -> 64x64 tile
    const int fr = lane & 15, sl = lane >> 4; // fragment row/col + k-slot

    f32x4 acc[4][4];
#pragma unroll
    for (int m = 0; m < 4; ++m)
#pragma unroll
        for (int n = 0; n < 4; ++n) acc[m][n] = (f32x4){0.f, 0.f, 0.f, 0.f};

    for (int k0 = 0; k0 < K; k0 += 32) {
#pragma unroll
        for (int q = 0; q < 2; ++q) {           // stage A (f32 -> bf16)
            const int slot = ah * 2 + q;        // k = k0 + slot*8 .. +7
            const float4 f0 = *reinterpret_cast<const float4*>(
                &Ap[(size_t)(arow + ar) * lda + k0 + slot * 8]);
            const float4 f1 = *reinterpret_cast<const float4*>(
                &Ap[(size_t)(arow + ar) * lda + k0 + slot * 8 + 4]);
            u16x8 pk;
            pk[0]=f2bf(f0.x); pk[1]=f2bf(f0.y); pk[2]=f2bf(f0.z); pk[3]=f2bf(f0.w);
            pk[4]=f2bf(f1.x); pk[5]=f2bf(f1.y); pk[6]=f2bf(f1.z); pk[7]=f2bf(f1.w);
            *reinterpret_cast<u16x8*>(&Asub[slot][ar][0]) = pk;
        }
#pragma unroll
        for (int q = 0; q < 2; ++q) {           // stage B transposed (k-contig per col)
            const int slot = bq * 2 + q;
            u16x8 pk;
#pragma unroll
            for (int j = 0; j < 8; ++j)
                pk[j] = f2bf(Bm[(size_t)(k0 + slot * 8 + j) * ldb + col0 + bc]);
            *reinterpret_cast<u16x8*>(&Bsub[slot][bc][0]) = pk;
        }
        __syncthreads();

        bf16x8 bfrag[4];
#pragma unroll
        for (int n = 0; n < 4; ++n)
            bfrag[n] = *reinterpret_cast<bf16x8*>(&Bsub[sl][wc * 64 + n * 16 + fr][0]);
#pragma unroll
        for (int m = 0; m < 4; ++m) {
            bf16x8 afrag = *reinterpret_cast<bf16x8*>(&Asub[sl][wr * 64 + m * 16 + fr][0]);
#pragma unroll
            for (int n = 0; n < 4; ++n)
                acc[m][n] = __builtin_amdgcn_mfma_f32_16x16x32_bf16(afrag, bfrag[n], acc[m][n], 0, 0, 0);
        }
        __syncthreads();
    }

    // C/D layout (m89-verified): col = lane&15, row = (lane>>4)*4 + reg
#pragma unroll
    for (int n = 0; n < 4; ++n) {
        const int col = col0 + wc * 64 + n * 16 + fr;
        if (col >= Nstore) continue;
        const float bs = bias[col];
#pragma unroll
        for (int m = 0; m < 4; ++m) {
            const int r = row0 + wr * 64 + m * 16 + sl * 4;
#pragma unroll
            for (int j = 0; j < 4; ++j)
                C[(size_t)(r + j) * ldc + col] = acc[m][n][j] + bs;
        }
    }
}

// concatenate [Woff | Waw | 0] -> Wcat [256][256], [boff|baw|0] -> bcat[256]
__global__ __launch_bounds__(256) void concat_w_kernel(
    const float* __restrict__ Woff, const float* __restrict__ Waw,
    const float* __restrict__ boff, const float* __restrict__ baw,
    float* __restrict__ Wcat, float* __restrict__ bcat)
{
    const int i = blockIdx.x * 256 + threadIdx.x;   // 0..65535
    const int k = i >> 8, j = i & 255;
    float val = 0.f;
    if (j < 96) val = Woff[k * 96 + j];
    else if (j < 192) val = Waw[k * 96 + (j - 96)];
    Wcat[i] = val;
    if (i < 256) bcat[i] = (i < 96) ? boff[i] : ((i < 192) ? baw[i - 96] : 0.f);
}

// per query: softmax the aw logits per-head (12-wide) and turn offsets into
// sample indices. rows layout per query (ld=192): [0..95]=off logits -> aw,
// [96..191]=aw logits -> sidx (roles swap on write, as in round 1).
__global__ __launch_bounds__(128) void softmax_sidx_kernel(
    const float* __restrict__ refpts, float* __restrict__ rows)
{
    const int bq = blockIdx.x;
    const int t = threadIdx.x;
    float* row = rows + (size_t)bq * 192;
    __shared__ float soff[96];
    __shared__ float sl[96];
    __shared__ float hm[8], hs[8];
    if (t < 96) { soff[t] = row[t]; sl[t] = row[96 + t]; }
    __syncthreads();
    if (t < 8) {
        float m = -1e30f;
        for (int j = 0; j < 12; ++j) m = fmaxf(m, sl[t * 12 + j]);
        hm[t] = m;
    }
    __syncthreads();
    if (t < 96) sl[t] = expf(sl[t] - hm[t / 12]);
    __syncthreads();
    if (t < 8) {
        float s = 0.f;
        for (int j = 0; j < 12; ++j) s += sl[t * 12 + j];
        hs[t] = s;
    }
    __syncthreads();
    if (t < 96) {
        row[t] = sl[t] / hs[t / 12];              // aw
        const int l = (t % 12) >> 2;
        const int T = 2048 >> l;
        const float ref = refpts[bq];
        float pos = ref + soff[t] / (float)T;
        pos = fminf(fmaxf(pos, 0.f), 1.f);
        row[96 + t] = pos * (float)(T - 1);        // sidx
    }
}

// gather + lerp + weighted sum:  out_mid[bq, h*32+c] = sum_{l,p} aw * lerp(vproj)
__global__ __launch_bounds__(256) void sample_kernel(
    const float* __restrict__ rows,   // [16384,192]  aw | sidx
    const float* __restrict__ vproj,  // [28672,128]  level-major
    float* __restrict__ out_mid)      // [16384,256]
{
    const int bq = blockIdx.x;
    const int b = bq >> 11;           // Q = 2048
    const int t = threadIdx.x;
    const int h = t >> 5, c = t & 31;
    __shared__ float srow[192];
    if (t < 192) srow[t] = rows[(size_t)bq * 192 + t];
    __syncthreads();
    float acc = 0.f;
#pragma unroll
    for (int l = 0; l < 3; ++l) {
        const int T = 2048 >> l;
        const int loff = (l == 0) ? 0 : ((l == 1) ? 16384 : 24576);
#pragma unroll
        for (int p = 0; p < 4; ++p) {
            const int j = h * 12 + l * 4 + p;
            const float w = srow[j];
            const float sidx = srow[96 + j];
            int ifl = (int)sidx;
            ifl = min(max(ifl, 0), T - 2);
            const float wce = sidx - (float)ifl;
            const size_t base = ((size_t)(loff + b * T + ifl)) * 128 + p * 32 + c;
            const float vf = vproj[base];
            const float vc = vproj[base + 128];
            acc += w * (vf + wce * (vc - vf));
        }
    }
    out_mid[(size_t)bq * 256 + t] = acc;
}

extern "C" void kernel_launch(void* const* d_in, const int* in_sizes, int n_in,
                              void* d_out, int out_size, void* d_ws, size_t ws_size,
                              hipStream_t stream) {
    (void)in_sizes; (void)n_in; (void)out_size; (void)ws_size;
    const float* query = (const float*)d_in[0];
    const float* refp  = (const float*)d_in[1];
    const float* v0    = (const float*)d_in[2];
    const float* v1    = (const float*)d_in[3];
    const float* v2    = (const float*)d_in[4];
    const float* Woff  = (const float*)d_in[5];
    const float* boff  = (const float*)d_in[6];
    const float* Waw   = (const float*)d_in[7];
    const float* baw   = (const float*)d_in[8];
    const float* Wv    = (const float*)d_in[9];
    const float* bv    = (const float*)d_in[10];
    const float* Wo    = (const float*)d_in[11];
    const float* bo    = (const float*)d_in[12];
    float* out = (float*)d_out;

    char* ws = (char*)d_ws;
    float* vproj = (float*)(ws);                               // 28672*128 f32 = 14,680,064 B
    float* rows  = (float*)(ws + 14680064);                    // 16384*192 f32 = 12,582,912 B
    float* omid  = (float*)(ws + 14680064 + 12582912);         // 16384*256 f32 = 16,777,216 B
    // Wcat/bcat live inside the (not-yet-written) omid region: consumed by the
    // offsets GEMM, which completes before sample_kernel writes omid.
    float* Wcat  = omid;                                       // 256*256 f32 = 262,144 B
    float* bcat  = (float*)((char*)omid + 262144);             // 256 f32

    const int HUGE = 1 << 30;

    // K0: weight concat (padded to 256 cols)
    concat_w_kernel<<<256, 256, 0, stream>>>(Woff, Waw, boff, baw, Wcat, bcat);

    // K1: fused value projections (all 3 levels, one launch, 224 blocks).
    // Only cols 0..127 of Wv are consumed (reference gathers head axis by p<4).
    gemm_mfma_kernel<<<dim3(1, 224), 256, 0, stream>>>(
        v0, v1, v2, 16384, 24576, 256, Wv, 256, bv, vproj, 128, 128, 256);

    // K2a: offset + attention-weight logits (N=256 computed, 192 stored)
    gemm_mfma_kernel<<<dim3(2, 128), 256, 0, stream>>>(
        query, query, query, HUGE, HUGE, 256, Wcat, 256, bcat, rows, 192, 192, 256);

    // K2b: per-head softmax + sample index computation
    softmax_sidx_kernel<<<16384, 128, 0, stream>>>(refp, rows);

    // K3: gather + lerp + weighted sum
    sample_kernel<<<16384, 256, 0, stream>>>(rows, vproj, omid);

    // K4: output projection
    gemm_mfma_kernel<<<dim3(2, 128), 256, 0, stream>>>(
        omid, omid, omid, HUGE, HUGE, 256, Wo, 256, bo, out, 256, 256, 256);
}